// Round 16
// baseline (88.398 us; speedup 1.0000x reference)
//
#include <hip/hip_runtime.h>
#include <math.h>

typedef __bf16 bf16;
typedef __bf16 bf16x4 __attribute__((ext_vector_type(4)));
typedef __bf16 bf16x8 __attribute__((ext_vector_type(8)));
typedef float f32x4 __attribute__((ext_vector_type(4)));

#define MFMA16(a,b,c) __builtin_amdgcn_mfma_f32_16x16x32_bf16((a),(b),(c),0,0,0)

static constexpr int HS  = 64;    // head size
static constexpr int SEQ = 2048;  // sequence length
static constexpr int NE  = 1024;  // n_embed
static constexpr int NB  = 8;     // batch

__device__ __forceinline__ bf16x8 cvt8v(f32x4 a, f32x4 b) {
  bf16x8 r;
  r[0]=(bf16)a[0]; r[1]=(bf16)a[1]; r[2]=(bf16)a[2]; r[3]=(bf16)a[3];
  r[4]=(bf16)b[0]; r[5]=(bf16)b[1]; r[6]=(bf16)b[2]; r[7]=(bf16)b[3];
  return r;
}

// ---- W f32 -> bf16 (Wq pre-scaled by 1/sqrt(64)) ----
__global__ __launch_bounds__(256) void wcvt_kernel(
    const float* __restrict__ Wq, const float* __restrict__ Wk,
    const float* __restrict__ Wv, bf16* __restrict__ wqb,
    bf16* __restrict__ wkb, bf16* __restrict__ wvb)
{
  int i = (blockIdx.x * 256 + threadIdx.x) * 4;   // 64 blocks -> 65536 elems
  float4 q = *(const float4*)(Wq + i);
  float4 k = *(const float4*)(Wk + i);
  float4 v = *(const float4*)(Wv + i);
  bf16x4 qo, ko, vo;
  qo[0]=(bf16)(q.x*0.125f); qo[1]=(bf16)(q.y*0.125f); qo[2]=(bf16)(q.z*0.125f); qo[3]=(bf16)(q.w*0.125f);
  ko[0]=(bf16)k.x; ko[1]=(bf16)k.y; ko[2]=(bf16)k.z; ko[3]=(bf16)k.w;
  vo[0]=(bf16)v.x; vo[1]=(bf16)v.y; vo[2]=(bf16)v.z; vo[3]=(bf16)v.w;
  *(bf16x4*)(wqb + i) = qo;
  *(bf16x4*)(wkb + i) = ko;
  *(bf16x4*)(wvb + i) = vo;
}

// ---- projection: whole-K panel, ONE barrier per block ----
// 1024 blocks x 512 thr. Even bid: Q block (32 index-rows); odd bid: KV block
// (32 memory-rows -> waves 0-3 compute k, 4-7 compute v; memory read ONCE).
// Stage: 32x1024 X panel f32 -> bf16 into 64 KB swizzled LDS (reg-staged,
// 8 x {2 float4 loads + ds_write_b128} per thread). ONE __syncthreads.
// K-reduction: W fragments in registers (one K-half at a time, plain arrays,
// compile-time indices; no asm clobbers in the loop -> no forced reloads),
// A-frags via swizzled ds_read_b128. Zero barriers, zero staging in the loop.
template<int KV>
__device__ __forceinline__ void proj_panel(
    const float* __restrict__ X, const bf16* __restrict__ W0,
    const bf16* __restrict__ W1, bf16* __restrict__ outA,
    bf16* __restrict__ outVT, int slab, bf16* __restrict__ Xs)
{
  const int tid  = threadIdx.x;
  const int lane = tid & 63;
  const int w    = tid >> 6;          // 0..7
  const int m    = lane & 15;
  const int g    = lane >> 4;
  const int rowBase = slab * 32;

  // ---- stage X panel: rows 0..31, cols 0..1023 (f32 -> bf16) ----
  {
    const int r   = tid >> 4;         // 0..31
    const int c16 = tid & 15;         // 32B-chunk index
    const float* xp = X + (size_t)(rowBase + r) * NE + c16 * 8;
    char* ldsrow = (char*)Xs + r * 2048;
#pragma unroll
    for (int i = 0; i < 8; ++i) {
      f32x4 a = *(const f32x4*)(xp + i*128);
      f32x4 b = *(const f32x4*)(xp + i*128 + 4);
      int seg = c16 + i*16;                       // 16B-seg 0..127
      *(bf16x8*)(ldsrow + 16*(seg ^ (r & 7))) = cvt8v(a, b);
    }
  }

  // ---- W fragments: wave role ----
  // Q:  rt = w>>2 (row-half), ct = w&3 (col-quarter) of the 64 outputs.
  // KV: mat = w>>2 (0=k, 1=v), ct = w&3; each wave does both row-halves.
  const bf16* wmat = !KV ? W0 : ((w < 4) ? W0 : W1);
  const bf16* wp   = wmat + (size_t)(16*(w & 3) + m) * NE + g * 8;

  bf16x8 wf[8][2];
#pragma unroll
  for (int kt = 0; kt < 8; ++kt) {
    wf[kt][0] = *(const bf16x8*)(wp + kt*64);
    wf[kt][1] = *(const bf16x8*)(wp + kt*64 + 32);
  }

  __syncthreads();                    // the ONLY barrier

  const f32x4 vz = {0.f,0.f,0.f,0.f};
  f32x4 acc0 = vz, acc1 = vz;         // Q: acc0 only. KV: row-halves 0,1.

#pragma unroll
  for (int half = 0; half < 2; ++half) {
    if (half == 1) {                  // reload W for kt 8..15 (no barrier
#pragma unroll                        //  in between -> regs stay live)
      for (int kt = 0; kt < 8; ++kt) {
        wf[kt][0] = *(const bf16x8*)(wp + (8 + kt)*64);
        wf[kt][1] = *(const bf16x8*)(wp + (8 + kt)*64 + 32);
      }
    }
#pragma unroll
    for (int kt = 0; kt < 8; ++kt) {
#pragma unroll
      for (int kk = 0; kk < 2; ++kk) {
        const int seg = (half*8 + kt)*8 + kk*4 + g;   // 16B-seg within row
        if (!KV) {
          const int arow = 16*(w >> 2) + m;
          bf16x8 af = *(const bf16x8*)((const char*)Xs + arow*2048 +
                                       16*(seg ^ (arow & 7)));
          acc0 = MFMA16(af, wf[kt][kk], acc0);
        } else {
          const int ar0 = m, ar1 = 16 + m;
          bf16x8 af0 = *(const bf16x8*)((const char*)Xs + ar0*2048 +
                                        16*(seg ^ (ar0 & 7)));
          bf16x8 af1 = *(const bf16x8*)((const char*)Xs + ar1*2048 +
                                        16*(seg ^ (ar1 & 7)));
          acc0 = MFMA16(af0, wf[kt][kk], acc0);
          acc1 = MFMA16(af1, wf[kt][kk], acc1);
        }
      }
    }
  }

  // ---- C/D: col = lane&15, row = 4*(lane>>4)+i  [m89-verified] ----
  const int h = 16*(w & 3) + m;
  if (!KV) {
#pragma unroll
    for (int i = 0; i < 4; ++i) {
      int row = rowBase + 16*(w >> 2) + 4*g + i;
      outA[(size_t)row * HS + h] = (bf16)acc0[i];
    }
  } else if (w < 4) {                 // k -> kb (row-major)
#pragma unroll
    for (int i = 0; i < 4; ++i) {
      int r0_ = rowBase + 4*g + i;
      outA[(size_t)r0_ * HS + h]        = (bf16)acc0[i];
      outA[(size_t)(r0_ + 16) * HS + h] = (bf16)acc1[i];
    }
  } else {                            // v -> vtb (transposed [B][64][SEQ])
#pragma unroll
    for (int i = 0; i < 4; ++i) {
      int r0_ = rowBase + 4*g + i;
      outVT[((size_t)(r0_ >> 11) * HS + h) * SEQ + (r0_ & 2047)] = (bf16)acc0[i];
      int r1_ = r0_ + 16;
      outVT[((size_t)(r1_ >> 11) * HS + h) * SEQ + (r1_ & 2047)] = (bf16)acc1[i];
    }
  }
}

__global__ __launch_bounds__(512, 4) void proj_kernel(
    const float* __restrict__ index, const float* __restrict__ memory,
    const bf16* __restrict__ wqb, const bf16* __restrict__ wkb,
    const bf16* __restrict__ wvb, bf16* __restrict__ qb,
    bf16* __restrict__ kb, bf16* __restrict__ vtb)
{
  __shared__ __align__(16) bf16 Xs[32 * 1024];   // 64 KB -> 2 blocks/CU
  const int bid  = blockIdx.x;
  const int slab = bid >> 1;                     // 0..511
  if ((bid & 1) == 0)
    proj_panel<0>(index,  wqb, nullptr, qb, nullptr, slab, Xs);
  else
    proj_panel<1>(memory, wkb, wvb,     kb, vtb,     slab, Xs);
}

// ---- flash attention: swapped-operand softmax (T12), unchanged ----
__global__ __launch_bounds__(128) void attn_kernel(
    const bf16* __restrict__ qb, const bf16* __restrict__ kb,
    const bf16* __restrict__ vtb, float* __restrict__ out)
{
  __shared__ __align__(16) bf16 Ks[2][64][72];    // per-wave K tile [kv][d]
  __shared__ __align__(16) bf16 VTs[2][64][72];   // per-wave V^T tile [d][kv]
  __shared__ __align__(16) bf16 Ps[2][16][72];    // per-wave P [q][kv]

  const int tid  = threadIdx.x;
  const int lane = tid & 63;
  const int w    = tid >> 6;
  const int m    = lane & 15;
  const int g    = lane >> 4;
  const int qt   = 127 - blockIdx.x;   // reversed: longest blocks first
  const int b    = blockIdx.y;
  const int nkv  = (qt >> 2) + 1;
  const int r0   = lane >> 1;
  const int hh   = (lane & 1) * 32;

  bf16x8 qf0 = *(const bf16x8*)(qb + ((size_t)b*SEQ + qt*16 + m)*HS + g*8);
  bf16x8 qf1 = *(const bf16x8*)(qb + ((size_t)b*SEQ + qt*16 + m)*HS + 32 + g*8);

  const f32x4 vz = {0.f,0.f,0.f,0.f};
  f32x4 o_acc[4] = {vz, vz, vz, vz};   // O^T[d=16nd+4g+i][q=m]
  float mrun = -INFINITY, lrun = 0.f;  // row-uniform state for q-row m

  bf16x8 kp[8], vp[8];
  const bf16* kbB = kb  + (size_t)b*SEQ*HS;
  const bf16* vtB = vtb + (size_t)b*HS*SEQ;

  auto loadKV = [&](int j) {
    const bf16* kt_ = kbB + (size_t)j*64*HS;
    const bf16* vt_ = vtB + j*64;
#pragma unroll
    for (int q = 0; q < 4; ++q) {
      kp[q]   = *(const bf16x8*)(kt_ + (size_t)r0*64        + hh + q*8);
      kp[4+q] = *(const bf16x8*)(kt_ + (size_t)(r0+32)*64   + hh + q*8);
      vp[q]   = *(const bf16x8*)(vt_ + (size_t)r0*SEQ       + hh + q*8);
      vp[4+q] = *(const bf16x8*)(vt_ + (size_t)(r0+32)*SEQ  + hh + q*8);
    }
  };
  auto writeKV = [&]() {
#pragma unroll
    for (int q = 0; q < 4; ++q) {
      *(bf16x8*)&Ks[w][r0][hh + q*8]      = kp[q];
      *(bf16x8*)&Ks[w][r0+32][hh + q*8]   = kp[4+q];
      *(bf16x8*)&VTs[w][r0][hh + q*8]     = vp[q];
      *(bf16x8*)&VTs[w][r0+32][hh + q*8]  = vp[4+q];
    }
  };

  int j = w;
  if (j < nkv) {
    loadKV(j);
    writeKV();
    while (true) {
      const int jn = j + 2;
      const bool more = jn < nkv;
      if (more) loadKV(jn);

      f32x4 s_acc[4];
#pragma unroll
      for (int na = 0; na < 4; ++na) {
        f32x4 z = vz;
        z = MFMA16(*(const bf16x8*)&Ks[w][16*na + m][g*8],      qf0, z);
        z = MFMA16(*(const bf16x8*)&Ks[w][16*na + m][32 + g*8], qf1, z);
        s_acc[na] = z;
      }
      if (j == nkv - 1) {   // causal mask: kv > q
        const int q_ = qt*16 + m;
#pragma unroll
        for (int na = 0; na < 4; ++na)
#pragma unroll
          for (int i = 0; i < 4; ++i)
            if (j*64 + 16*na + 4*g + i > q_) s_acc[na][i] = -INFINITY;
      }

      float mx = fmaxf(
        fmaxf(fmaxf(fmaxf(s_acc[0][0],s_acc[0][1]),fmaxf(s_acc[0][2],s_acc[0][3])),
              fmaxf(fmaxf(s_acc[1][0],s_acc[1][1]),fmaxf(s_acc[1][2],s_acc[1][3]))),
        fmaxf(fmaxf(fmaxf(s_acc[2][0],s_acc[2][1]),fmaxf(s_acc[2][2],s_acc[2][3])),
              fmaxf(fmaxf(s_acc[3][0],s_acc[3][1]),fmaxf(s_acc[3][2],s_acc[3][3]))));
      mx = fmaxf(mx, __shfl_xor(mx, 16));
      mx = fmaxf(mx, __shfl_xor(mx, 32));   // row max over all 64 kv
      float mnew = fmaxf(mrun, mx);
      float corr = __expf(mrun - mnew);
      mrun = mnew;
      float ts = 0.f;
#pragma unroll
      for (int na = 0; na < 4; ++na) {
        bf16x4 pk;
#pragma unroll
        for (int i = 0; i < 4; ++i) {
          float p = __expf(s_acc[na][i] - mnew);
          ts += p;
          pk[i] = (bf16)p;
        }
        *(bf16x4*)&Ps[w][m][16*na + 4*g] = pk;
      }
      ts += __shfl_xor(ts, 16);
      ts += __shfl_xor(ts, 32);
      lrun = lrun * corr + ts;
#pragma unroll
      for (int nd = 0; nd < 4; ++nd)
#pragma unroll
        for (int i = 0; i < 4; ++i) o_acc[nd][i] *= corr;

      bf16x8 pf0 = *(const bf16x8*)&Ps[w][m][g*8];
      bf16x8 pf1 = *(const bf16x8*)&Ps[w][m][32 + g*8];
#pragma unroll
      for (int nd = 0; nd < 4; ++nd) {
        o_acc[nd] = MFMA16(*(const bf16x8*)&VTs[w][16*nd + m][g*8],      pf0, o_acc[nd]);
        o_acc[nd] = MFMA16(*(const bf16x8*)&VTs[w][16*nd + m][32 + g*8], pf1, o_acc[nd]);
      }

      if (!more) break;
      writeKV();
      j = jn;
    }
  }

  float* PO = (float*)&Ks[w][0][0];    // 16 x 68 f32
  float* PM = (float*)&VTs[w][0][0];   // m[16], l[16]
#pragma unroll
  for (int nd = 0; nd < 4; ++nd)
    *(f32x4*)&PO[m*68 + 16*nd + 4*g] = o_acc[nd];
  if (g == 0) { PM[m] = mrun; PM[16 + m] = lrun; }
  __syncthreads();

  {
    const int r  = tid >> 3;
    const int c0 = (tid & 7) * 8;
    const float* O0 = (const float*)&Ks[0][0][0];
    const float* O1 = (const float*)&Ks[1][0][0];
    const float* M0 = (const float*)&VTs[0][0][0];
    const float* M1 = (const float*)&VTs[1][0][0];
    float m0 = M0[r], l0 = M0[16 + r];
    float m1 = M1[r], l1 = M1[16 + r];
    float mx = fmaxf(m0, m1);
    float s0 = __expf(m0 - mx), s1 = __expf(m1 - mx);
    float inv = 1.f / (s0*l0 + s1*l1);
    float4 x0 = *(const float4*)(O0 + r*68 + c0);
    float4 x1 = *(const float4*)(O0 + r*68 + c0 + 4);
    float4 y0 = *(const float4*)(O1 + r*68 + c0);
    float4 y1 = *(const float4*)(O1 + r*68 + c0 + 4);
    float4 o0, o1;
    o0.x=(x0.x*s0+y0.x*s1)*inv; o0.y=(x0.y*s0+y0.y*s1)*inv;
    o0.z=(x0.z*s0+y0.z*s1)*inv; o0.w=(x0.w*s0+y0.w*s1)*inv;
    o1.x=(x1.x*s0+y1.x*s1)*inv; o1.y=(x1.y*s0+y1.y*s1)*inv;
    o1.z=(x1.z*s0+y1.z*s1)*inv; o1.w=(x1.w*s0+y1.w*s1)*inv;
    float* op = out + ((size_t)b*SEQ + qt*16 + r) * HS + c0;
    *(float4*)(op)     = o0;
    *(float4*)(op + 4) = o1;
  }
}

extern "C" void kernel_launch(void* const* d_in, const int* in_sizes, int n_in,
                              void* d_out, int out_size, void* d_ws, size_t ws_size,
                              hipStream_t stream) {
  (void)in_sizes; (void)n_in; (void)out_size; (void)ws_size;
  const float* index  = (const float*)d_in[0];
  const float* memory = (const float*)d_in[1];
  const float* Wq     = (const float*)d_in[2];
  const float* Wk     = (const float*)d_in[3];
  const float* Wv     = (const float*)d_in[4];
  float* out = (float*)d_out;

  bf16* qb  = (bf16*)d_ws;                          // [NB*SEQ][64]
  bf16* kb  = qb  + (size_t)NB * SEQ * HS;          // [NB*SEQ][64]
  bf16* vtb = kb  + (size_t)NB * SEQ * HS;          // [NB][64][SEQ]
  bf16* wqb = vtb + (size_t)NB * SEQ * HS;          // [64][1024] (pre-scaled)
  bf16* wkb = wqb + (size_t)HS * NE;
  bf16* wvb = wkb + (size_t)HS * NE;

  wcvt_kernel<<<dim3(64), 256, 0, stream>>>(Wq, Wk, Wv, wqb, wkb, wvb);
  proj_kernel<<<dim3(1024), 512, 0, stream>>>(index, memory, wqb, wkb, wvb, qb, kb, vtb);
  attn_kernel<<<dim3(128, 8), 128, 0, stream>>>(qb, kb, vtb, out);
}